// Round 6
// baseline (170.023 us; speedup 1.0000x reference)
//
#include <hip/hip_runtime.h>
#include <hip/hip_bf16.h>

#define NROWS 131072
#define KEXP 16
#define MPC 128
#define DIMD 64

typedef float f32x4  __attribute__((ext_vector_type(4)));
typedef float f32x16 __attribute__((ext_vector_type(16)));
typedef short s16x8  __attribute__((ext_vector_type(8)));

#define L2E 1.4426950408889634f
#define LN2 0.6931471805599453f

static __device__ inline unsigned int b2u(__hip_bfloat162 h) {
    union { __hip_bfloat162 h; unsigned int u; } c;
    c.h = h;
    return c.u;
}

// pack 8 fp32 (scaled) -> 8 bf16 in an int4
static __device__ inline int4 cvt8s(float4 f0, float4 f1, float sc) {
    __hip_bfloat162 p0 = __float22bfloat162_rn(make_float2(f0.x * sc, f0.y * sc));
    __hip_bfloat162 p1 = __float22bfloat162_rn(make_float2(f0.z * sc, f0.w * sc));
    __hip_bfloat162 p2 = __float22bfloat162_rn(make_float2(f1.x * sc, f1.y * sc));
    __hip_bfloat162 p3 = __float22bfloat162_rn(make_float2(f1.z * sc, f1.w * sc));
    int4 pk;
    pk.x = (int)b2u(p0); pk.y = (int)b2u(p1); pk.z = (int)b2u(p2); pk.w = (int)b2u(p3);
    return pk;
}

// async 16B/lane global->LDS DMA (wave-uniform LDS base + lane*16)
static __device__ inline void async_copy16(const void* g, void* l) {
    __builtin_amdgcn_global_load_lds(
        (const __attribute__((address_space(1))) unsigned int*)g,
        (__attribute__((address_space(3))) unsigned int*)l, 16, 0, 0);
}

// prep: abff = bf16(a * log2e) in 32x32x16 A-fragment order:
//   unit u (16B) : k = u>>10, fb = (u>>6)&15, ul = u&63, mt = fb>>2, c = fb&3
//   value j=0..7 : a[k][mt*32 + (ul&31)][c*16 + (ul>>5)*8 + j] * L2E
// lbf = b * L2E  (8 KB)
__global__ void prep_kernel(const float* __restrict__ a, const float* __restrict__ b,
                            short* __restrict__ abff, float* __restrict__ lbf) {
    if (blockIdx.x < 64) {
        const int u   = blockIdx.x * 256 + threadIdx.x;   // 0..16383
        const int k   = u >> 10;
        const int rem = u & 1023;
        const int fb  = rem >> 6;
        const int ul  = rem & 63;
        const int mt  = fb >> 2, c = fb & 3;
        const float* p = a + (size_t)(k * MPC + mt * 32 + (ul & 31)) * DIMD
                           + c * 16 + (ul >> 5) * 8;
        float4 f0 = *(const float4*)(p);
        float4 f1 = *(const float4*)(p + 4);
        *(int4*)(abff + (size_t)u * 8) = cvt8s(f0, f1, L2E);
    } else {
        const int t = threadIdx.x;
        float4 v0 = *(const float4*)(b + t * 8);
        float4 v1 = *(const float4*)(b + t * 8 + 4);
        float4 o0 = {v0.x * L2E, v0.y * L2E, v0.z * L2E, v0.w * L2E};
        float4 o1 = {v1.x * L2E, v1.y * L2E, v1.z * L2E, v1.w * L2E};
        *(float4*)(lbf + t * 8)     = o0;
        *(float4*)(lbf + t * 8 + 4) = o1;
    }
}

// Block = 256 threads (4 waves); wave owns 64 rows (2 n-tiles) of x PERSISTENT
// in registers (Bf[2][4], 32 VGPR). Block covers 256 rows x 8 experts
// (family = blockIdx&1 -> experts family*8..+7); grid = 1024 (4 blocks/CU).
// Per expert: A (bf16 x log2e, frag-ordered) DMA'd global->LDS double-buffered
// via global_load_lds dwordx4 (no staging VALU); bias b*log2e folded into MFMA
// C-init via broadcast LDS reads. Softmax m-sum is in-lane + ONE shfl_xor(32).
// Families combine via 2-way atomicAdd on out (262k atomics, ~free).
__global__ __launch_bounds__(256, 4)
void fused_kernel(const float* __restrict__ x, const float* __restrict__ s,
                  const short* __restrict__ abff, const float* __restrict__ lbf,
                  float* __restrict__ out) {
    __shared__ int4  abuf[2][1024];   // 2 x 16 KB, one expert's A-frags each
    __shared__ float lb[KEXP * MPC];  // 8 KB bias*log2e table

    const int tid  = threadIdx.x;
    const int w    = tid >> 6;
    const int l    = tid & 63;
    const int ln   = l & 31;
    const int half = l >> 5;

    const int family = blockIdx.x & 1;
    const int r0w    = (blockIdx.x >> 1) * 256 + w * 64;

    // stage bias table once (8 KB)
    {
        float4 v0 = *(const float4*)(lbf + tid * 8);
        float4 v1 = *(const float4*)(lbf + tid * 8 + 4);
        *(float4*)(lb + tid * 8)     = v0;
        *(float4*)(lb + tid * 8 + 4) = v1;
    }

    // persistent x B-fragments: Bf[nt][c] = x[r0w + nt*32 + ln][c*16 + half*8 ..+7]
    union { int4 i; s16x8 v; } Bf[2][4];
#pragma unroll
    for (int nt = 0; nt < 2; ++nt)
#pragma unroll
        for (int c = 0; c < 4; ++c) {
            const float* gp = x + (size_t)(r0w + nt * 32 + ln) * DIMD + c * 16 + half * 8;
            float4 f0 = *(const float4*)(gp);
            float4 f1 = *(const float4*)(gp + 4);
            Bf[nt][c].i = cvt8s(f0, f1, 1.0f);
        }

    // DMA expert (family*8) into abuf[0]: wave w covers chunks w*4 .. w*4+3
    {
        const short* src = abff + (size_t)(family * 8) * 8192;
#pragma unroll
        for (int i = 0; i < 4; ++i) {
            const int chunk = w * 4 + i;
            async_copy16(src + chunk * 512 + l * 8,
                         (char*)&abuf[0][0] + chunk * 1024);
        }
    }
    __syncthreads();   // drains DMA (vmcnt) + lb stores

    float racc0 = 0.f, racc1 = 0.f;

    for (int k = 0; k < 8; ++k) {
        const int kf = family * 8 + k;
        const int kb = k & 1;

        // issue next expert's DMA into the other buffer (in flight during compute)
        if (k + 1 < 8) {
            const short* src = abff + (size_t)(kf + 1) * 8192;
#pragma unroll
            for (int i = 0; i < 4; ++i) {
                const int chunk = w * 4 + i;
                async_copy16(src + chunk * 512 + l * 8,
                             (char*)&abuf[kb ^ 1][0] + chunk * 1024);
            }
        }

        const float sk2 = s[kf] * LN2;
        float esum0 = 0.f, esum1 = 0.f;

#pragma unroll
        for (int mt = 0; mt < 4; ++mt) {
            // A-frags for this mtile (conflict-free b128: lane l -> l*16B)
            s16x8 Af[4];
#pragma unroll
            for (int c = 0; c < 4; ++c)
                Af[c] = *(const s16x8*)((const short*)&abuf[kb][0] + (mt * 4 + c) * 512 + l * 8);

            // bias C-init: lbv[g][j] = lb[kf*128 + mt*32 + g*8 + half*4 + j]
            // (C/D row m = j + 8g + 4*half + 32*mt  — round-5-verified layout)
            union { f32x4 q[4]; f32x16 v; } acc_a, acc_b;
#pragma unroll
            for (int g = 0; g < 4; ++g) {
                f32x4 t = *(const f32x4*)(lb + kf * MPC + mt * 32 + g * 8 + half * 4);
                acc_a.q[g] = t;
                acc_b.q[g] = t;
            }

            // two independent 4-deep MFMA chains (n-tiles 0 and 1)
#pragma unroll
            for (int c = 0; c < 4; ++c)
                acc_a.v = __builtin_amdgcn_mfma_f32_32x32x16_bf16(Af[c], Bf[0][c].v, acc_a.v, 0, 0, 0);
#pragma unroll
            for (int c = 0; c < 4; ++c)
                acc_b.v = __builtin_amdgcn_mfma_f32_32x32x16_bf16(Af[c], Bf[1][c].v, acc_b.v, 0, 0, 0);

            // in-lane sum of exp2 over this mtile's 16 m-rows (tree)
            float ta[8], tb[8];
#pragma unroll
            for (int r = 0; r < 8; ++r) {
                ta[r] = __builtin_amdgcn_exp2f(acc_a.v[2 * r]) + __builtin_amdgcn_exp2f(acc_a.v[2 * r + 1]);
                tb[r] = __builtin_amdgcn_exp2f(acc_b.v[2 * r]) + __builtin_amdgcn_exp2f(acc_b.v[2 * r + 1]);
            }
#pragma unroll
            for (int r = 0; r < 4; ++r) { ta[r] += ta[r + 4]; tb[r] += tb[r + 4]; }
            esum0 += (ta[0] + ta[1]) + (ta[2] + ta[3]);
            esum1 += (tb[0] + tb[1]) + (tb[2] + tb[3]);
        }

        // combine m-halves (lanes l and l^32), accumulate weighted lse
        float tot0 = esum0 + __shfl_xor(esum0, 32);
        float tot1 = esum1 + __shfl_xor(esum1, 32);
        racc0 = fmaf(sk2, __log2f(tot0), racc0);
        racc1 = fmaf(sk2, __log2f(tot1), racc1);

        __syncthreads();   // all waves done with abuf[kb]; next DMA drained
    }

    // half 0 lanes own n-tile 0 rows, half 1 lanes own n-tile 1 rows
    atomicAdd(&out[r0w + half * 32 + ln], half ? racc1 : racc0);
}

extern "C" void kernel_launch(void* const* d_in, const int* in_sizes, int n_in,
                              void* d_out, int out_size, void* d_ws, size_t ws_size,
                              hipStream_t stream) {
    const float* x = (const float*)d_in[0];
    const float* s = (const float*)d_in[1];
    const float* a = (const float*)d_in[2];
    const float* b = (const float*)d_in[3];
    float* out = (float*)d_out;

    short* abff = (short*)d_ws;                          // 256 KB frag-ordered bf16 A
    float* lbf  = (float*)((char*)d_ws + 262144);        // 8 KB bias*log2e

    hipMemsetAsync(d_out, 0, (size_t)NROWS * sizeof(float), stream);
    prep_kernel<<<65, 256, 0, stream>>>(a, b, abff, lbf);
    fused_kernel<<<NROWS / 128, 256, 0, stream>>>(x, s, abff, lbf, out);
}

// Round 7
// 121.947 us; speedup vs baseline: 1.3942x; 1.3942x over previous
//
#include <hip/hip_runtime.h>
#include <hip/hip_bf16.h>

#define NROWS 131072
#define KEXP 16
#define MPC 128
#define DIMD 64

typedef float f32x4  __attribute__((ext_vector_type(4)));
typedef float f32x16 __attribute__((ext_vector_type(16)));
typedef short s16x8  __attribute__((ext_vector_type(8)));

#define L2E 1.4426950408889634f
#define LN2 0.6931471805599453f

static __device__ inline unsigned int b2u(__hip_bfloat162 h) {
    union { __hip_bfloat162 h; unsigned int u; } c;
    c.h = h;
    return c.u;
}

static __device__ inline int4 cvt8s(float4 f0, float4 f1, float sc) {
    __hip_bfloat162 p0 = __float22bfloat162_rn(make_float2(f0.x * sc, f0.y * sc));
    __hip_bfloat162 p1 = __float22bfloat162_rn(make_float2(f0.z * sc, f0.w * sc));
    __hip_bfloat162 p2 = __float22bfloat162_rn(make_float2(f1.x * sc, f1.y * sc));
    __hip_bfloat162 p3 = __float22bfloat162_rn(make_float2(f1.z * sc, f1.w * sc));
    int4 pk;
    pk.x = (int)b2u(p0); pk.y = (int)b2u(p1); pk.z = (int)b2u(p2); pk.w = (int)b2u(p3);
    return pk;
}

// async 16B/lane global->LDS DMA (wave-uniform LDS base + lane*16)
static __device__ inline void async_copy16(const void* g, void* l) {
    __builtin_amdgcn_global_load_lds(
        (const __attribute__((address_space(1))) unsigned int*)g,
        (__attribute__((address_space(3))) unsigned int*)l, 16, 0, 0);
}

// abff: per expert 20 chunks [mt(4)][c(5)] of 64 int4 (1 KB each) = 20 KB.
//   c<4 : A-frag, value j = a[k][mt*32 + (ul&31)][c*16 + (ul>>5)*8 + j] * L2E
//   c==4: bias chunk — A[m][k'=0] = b[k][mt*32+m] * L2E (ul<32, element 0), else 0
__global__ void prep_kernel(const float* __restrict__ a, const float* __restrict__ b,
                            short* __restrict__ abff) {
    const int u   = blockIdx.x * 256 + threadIdx.x;   // 0..20479
    const int k   = u / 1280;
    const int rem = u - k * 1280;
    const int mt  = rem / 320;
    const int rc  = rem - mt * 320;
    const int c   = rc >> 6;
    const int ul  = rc & 63;
    int4 pk;
    if (c < 4) {
        const float* p = a + (size_t)(k * MPC + mt * 32 + (ul & 31)) * DIMD
                           + c * 16 + (ul >> 5) * 8;
        pk = cvt8s(*(const float4*)(p), *(const float4*)(p + 4), L2E);
    } else {
        pk.x = 0; pk.y = 0; pk.z = 0; pk.w = 0;
        if (ul < 32) {
            union { __hip_bfloat16 h; unsigned short us; } cv;
            cv.h = __float2bfloat16(b[k * MPC + mt * 32 + ul] * L2E);
            pk.x = (int)cv.us;   // element 0 = bias, elements 1..7 = 0
        }
    }
    *(int4*)(abff + (size_t)u * 8) = pk;
}

// Block = 256 threads (4 waves); wave owns 64 rows (2 n-tiles) of x PERSISTENT in
// registers (Bf[2][4], 32 VGPR). family = blockIdx&1 -> experts family*8..+7;
// grid = 1024 -> 4 blocks/CU (LDS 2x20KB = 40KB exactly 4/CU).
// Per expert: extended A (4 data chunks + 1 bias chunk per mtile) DMA'd
// global->LDS double-buffered (global_load_lds dwordx4, zero staging VALU).
// MFMA 32x32x16 transposed (m on C-rows): bias enters as 5th MFMA with
// constant B (1.0 at k'=0). Softmax m-sum in-lane + ONE shfl_xor(32)/expert.
// Sequential n-tile chains keep one live f32x16 acc (~98 regs, fits 128 budget).
__global__ __launch_bounds__(256, 4)
void fused_kernel(const float* __restrict__ x, const float* __restrict__ s,
                  const short* __restrict__ abff, float* __restrict__ out) {
    __shared__ int4 abuf[2][1280];   // 2 x 20 KB

    const int tid  = threadIdx.x;
    const int w    = tid >> 6;
    const int l    = tid & 63;
    const int ln   = l & 31;
    const int half = l >> 5;

    const int family = blockIdx.x & 1;
    const int r0w    = (blockIdx.x >> 1) * 256 + w * 64;

    // persistent x B-fragments: Bf[nt][c] = x[r0w + nt*32 + ln][c*16 + half*8 ..+7]
    union { int4 i; s16x8 v; } Bf[2][4];
#pragma unroll
    for (int nt = 0; nt < 2; ++nt)
#pragma unroll
        for (int c = 0; c < 4; ++c) {
            const float* gp = x + (size_t)(r0w + nt * 32 + ln) * DIMD + c * 16 + half * 8;
            float4 f0 = *(const float4*)(gp);
            float4 f1 = *(const float4*)(gp + 4);
            Bf[nt][c].i = cvt8s(f0, f1, 1.0f);
        }

    // constant bias-B: B[n][k'=0] = 1.0 (k'=0 lives on half==0 lanes, element 0)
    union { int4 i; s16x8 v; } Bones;
    Bones.i.x = (half == 0) ? 0x3F80 : 0;   // bf16(1.0) in element 0
    Bones.i.y = 0; Bones.i.z = 0; Bones.i.w = 0;

    // DMA first expert into abuf[0]: wave w covers chunks w*5 .. w*5+4
    {
        const short* src = abff + (size_t)(family * 8) * 10240;
#pragma unroll
        for (int i = 0; i < 5; ++i) {
            const int ch = w * 5 + i;
            async_copy16(src + ch * 512 + l * 8, (char*)&abuf[0][0] + ch * 1024);
        }
    }
    __syncthreads();   // barrier drains DMA (vmcnt0 before s_barrier)

    float racc0 = 0.f, racc1 = 0.f;

    for (int k = 0; k < 8; ++k) {
        const int kf = family * 8 + k;
        const int kb = k & 1;

        // next expert's DMA into the other buffer (in flight during compute)
        if (k + 1 < 8) {
            const short* src = abff + (size_t)(kf + 1) * 10240;
#pragma unroll
            for (int i = 0; i < 5; ++i) {
                const int ch = w * 5 + i;
                async_copy16(src + ch * 512 + l * 8,
                             (char*)&abuf[kb ^ 1][0] + ch * 1024);
            }
        }

        const float sk2 = s[kf] * LN2;
        float esum0 = 0.f, esum1 = 0.f;

#pragma unroll
        for (int mt = 0; mt < 4; ++mt) {
            // A-frags incl. bias chunk (conflict-free b128: lane l -> l*16B)
            s16x8 Af[5];
#pragma unroll
            for (int c = 0; c < 5; ++c)
                Af[c] = *(const s16x8*)((const short*)&abuf[kb][0] + (mt * 5 + c) * 512 + l * 8);

            // ---- n-tile 0 chain ----
            {
                f32x16 acc = {};
#pragma unroll
                for (int c = 0; c < 4; ++c)
                    acc = __builtin_amdgcn_mfma_f32_32x32x16_bf16(Af[c], Bf[0][c].v, acc, 0, 0, 0);
                acc = __builtin_amdgcn_mfma_f32_32x32x16_bf16(Af[4], Bones.v, acc, 0, 0, 0);
                float s0 = 0.f, s1 = 0.f, s2 = 0.f, s3 = 0.f;
#pragma unroll
                for (int r = 0; r < 4; ++r) {
                    s0 += __builtin_amdgcn_exp2f(acc[4 * r + 0]);
                    s1 += __builtin_amdgcn_exp2f(acc[4 * r + 1]);
                    s2 += __builtin_amdgcn_exp2f(acc[4 * r + 2]);
                    s3 += __builtin_amdgcn_exp2f(acc[4 * r + 3]);
                }
                esum0 += (s0 + s1) + (s2 + s3);
            }
            // ---- n-tile 1 chain ----
            {
                f32x16 acc = {};
#pragma unroll
                for (int c = 0; c < 4; ++c)
                    acc = __builtin_amdgcn_mfma_f32_32x32x16_bf16(Af[c], Bf[1][c].v, acc, 0, 0, 0);
                acc = __builtin_amdgcn_mfma_f32_32x32x16_bf16(Af[4], Bones.v, acc, 0, 0, 0);
                float s0 = 0.f, s1 = 0.f, s2 = 0.f, s3 = 0.f;
#pragma unroll
                for (int r = 0; r < 4; ++r) {
                    s0 += __builtin_amdgcn_exp2f(acc[4 * r + 0]);
                    s1 += __builtin_amdgcn_exp2f(acc[4 * r + 1]);
                    s2 += __builtin_amdgcn_exp2f(acc[4 * r + 2]);
                    s3 += __builtin_amdgcn_exp2f(acc[4 * r + 3]);
                }
                esum1 += (s0 + s1) + (s2 + s3);
            }
        }

        // combine m-halves (lanes l and l^32), accumulate weighted lse
        float tot0 = esum0 + __shfl_xor(esum0, 32);
        float tot1 = esum1 + __shfl_xor(esum1, 32);
        racc0 = fmaf(sk2, __log2f(tot0), racc0);
        racc1 = fmaf(sk2, __log2f(tot1), racc1);

        __syncthreads();   // abuf[kb] free for next DMA; next buffer drained
    }

    // half 0 lanes own n-tile 0 rows, half 1 lanes own n-tile 1 rows
    atomicAdd(&out[r0w + half * 32 + ln], half ? racc1 : racc0);
}

extern "C" void kernel_launch(void* const* d_in, const int* in_sizes, int n_in,
                              void* d_out, int out_size, void* d_ws, size_t ws_size,
                              hipStream_t stream) {
    const float* x = (const float*)d_in[0];
    const float* s = (const float*)d_in[1];
    const float* a = (const float*)d_in[2];
    const float* b = (const float*)d_in[3];
    float* out = (float*)d_out;

    short* abff = (short*)d_ws;   // 16 experts x 20 KB = 320 KB

    hipMemsetAsync(d_out, 0, (size_t)NROWS * sizeof(float), stream);
    prep_kernel<<<80, 256, 0, stream>>>(a, b, abff);
    fused_kernel<<<NROWS / 128, 256, 0, stream>>>(x, s, abff, out);
}